// Round 5
// baseline (208.060 us; speedup 1.0000x reference)
//
#include <hip/hip_runtime.h>
#include <hip/hip_bf16.h>

// ---------------------------------------------------------------------------
// WeightOnlyBlockwiseQuantizedLinear: out[m][n] = sum_s scaler[s][n] *
//   sum_{c<128} W[s][c][n] * x[m][s*128+c],  m = b*D+d (2048), n (4096)
//
// R4 (resubmit; R4 bench was an acquisition timeout):
// (1) GEMM with true register software-pipelining (m201 mechanism):
//     16-MFMA phases; fragments for phase p+1 ds_read during phase p.
// (2) prep_b: zero-LDS register 8x8 transpose, coalesced both sides.
// ---------------------------------------------------------------------------

#define MDIM 2048
#define NDIM 4096
#define KDIM 4096
#define NBLK 32
#define BM 128
#define BN 256
#define BK 64
#define NT (KDIM / BK)   // 64 K-tiles

typedef __attribute__((ext_vector_type(8))) short bf16x8;
typedef __attribute__((ext_vector_type(4))) float f32x4;
typedef __attribute__((ext_vector_type(8))) unsigned short u16x8;

__device__ __forceinline__ unsigned short f2bf(float f) {
  unsigned u = __float_as_uint(f);
  u += 0x7fffu + ((u >> 16) & 1u);   // round-to-nearest-even
  return (unsigned short)(u >> 16);
}

__device__ __forceinline__ void gl_lds16(const void* g, void* l) {
  __builtin_amdgcn_global_load_lds(
      (const __attribute__((address_space(1))) unsigned int*)g,
      (__attribute__((address_space(3))) unsigned int*)l,
      16, 0, 0);
}

// ---- prep A: fp32 x -> bf16 ----------------------------------------------
__global__ void prep_a_kernel(const float* __restrict__ x,
                              unsigned short* __restrict__ ab) {
  int i = blockIdx.x * blockDim.x + threadIdx.x;  // group of 4 floats
  const float4 v = reinterpret_cast<const float4*>(x)[i];
  ushort4 hv;
  hv.x = f2bf(v.x); hv.y = f2bf(v.y); hv.z = f2bf(v.z); hv.w = f2bf(v.w);
  reinterpret_cast<ushort4*>(ab)[i] = hv;
}

// ---- prep B: W int32 [K][N] * scaler -> bf16 W^T [N][K] -------------------
// Zero-LDS: per-thread 8x8 register transpose. Reads: at fixed r, lanes
// {i,i+16,i+32,i+48} cover 128 contiguous bytes of one W row. Writes: at
// fixed j, 16 lanes write 256 contiguous bytes of one bt row. Dequant in regs.
__global__ void prep_b_kernel(const int* __restrict__ w,
                              const float* __restrict__ scaler,
                              unsigned short* __restrict__ bt) {
  const int t = threadIdx.x;
  const int n0 = blockIdx.x * 128;
  const int k0 = blockIdx.y * 128;
  const int s = blockIdx.y;            // 128-k tile == one scaler block
  const int k8 = (t & 15) * 8;
  const int n8 = (t >> 4) * 8;

  float sc[8];
  {
    const float4* scv = reinterpret_cast<const float4*>(scaler + (size_t)s * NDIM + n0 + n8);
    const float4 s0 = scv[0], s1 = scv[1];
    sc[0] = s0.x; sc[1] = s0.y; sc[2] = s0.z; sc[3] = s0.w;
    sc[4] = s1.x; sc[5] = s1.y; sc[6] = s1.z; sc[7] = s1.w;
  }
  u16x8 outv[8];
#pragma unroll
  for (int r = 0; r < 8; ++r) {
    const int4* src = reinterpret_cast<const int4*>(w + (size_t)(k0 + k8 + r) * NDIM + n0 + n8);
    const int4 a = src[0], b = src[1];
    const int v[8] = {a.x, a.y, a.z, a.w, b.x, b.y, b.z, b.w};
#pragma unroll
    for (int j = 0; j < 8; ++j) outv[j][r] = f2bf((float)v[j] * sc[j]);
  }
#pragma unroll
  for (int j = 0; j < 8; ++j)
    *reinterpret_cast<u16x8*>(bt + (size_t)(n0 + n8 + j) * KDIM + k0 + k8) = outv[j];
}

// ---- main GEMM: pipelined 2-phase/K-tile, 16 MFMA per phase ---------------
#define MFMA_BF16 __builtin_amdgcn_mfma_f32_16x16x32_bf16

__global__ __launch_bounds__(512, 2)
void gemm_kernel(const unsigned short* __restrict__ ab,
                 const unsigned short* __restrict__ bt,
                 float* __restrict__ out) {
  // [A0 16K][A1 16K][B0 32K][B1 32K] = 96 KB
  __shared__ __align__(16) char lds[98304];

  const int t = threadIdx.x;
  const int lane = t & 63;
  const int wid = t >> 6;         // 0..7
  const int wm = wid >> 2;        // 0..1  (64-row band)
  const int wn = wid & 3;         // 0..3  (64-col band)
  const int lane15 = lane & 15;
  const int laneq = lane >> 4;    // 0..3
  const int swz = (lane & 7) << 4;

  // XCD-aware swizzle; 256 % 8 == 0 -> bijective
  const unsigned flat = blockIdx.x;
  const unsigned swzb = (flat & 7u) * 32u + (flat >> 3);
  const int ntile = swzb & 15;
  const int mtile = swzb >> 4;
  const int m0 = mtile * BM;
  const int n0 = ntile * BN;

  // staging: 512 thr x 16B = 8 KB = 64 rows x 128 B per issue
  const int srow = t >> 3;                    // 0..63
  const int sslot = (t & 7) ^ (srow & 7);     // inverse of read-side XOR
  const char* ga = (const char*)ab + ((size_t)(m0 + srow) * KDIM) * 2 + sslot * 16;
  const char* gb = (const char*)bt + ((size_t)(n0 + srow) * KDIM) * 2 + sslot * 16;
  const size_t rstep = (size_t)64 * KDIM * 2;  // +64 rows per issue

  char* const lA0 = lds + (size_t)wid * 1024;           // + c*16384
  char* const lB0 = lds + 32768 + (size_t)wid * 1024;   // + c*32768

#define STAGE(kt, c) do {                                   \
    const size_t ko_ = (size_t)(kt) * (BK * 2);             \
    char* a_ = lA0 + (c) * 16384;                           \
    char* b_ = lB0 + (c) * 32768;                           \
    gl_lds16(ga + ko_,             a_);                     \
    gl_lds16(ga + ko_ + rstep,     a_ + 8192);              \
    gl_lds16(gb + ko_,             b_);                     \
    gl_lds16(gb + ko_ + rstep,     b_ + 8192);              \
    gl_lds16(gb + ko_ + 2 * rstep, b_ + 16384);             \
    gl_lds16(gb + ko_ + 3 * rstep, b_ + 24576);             \
  } while (0)

  int offA[4], offB[4];
#pragma unroll
  for (int i = 0; i < 4; ++i) {
    offA[i] = (wm * 64 + i * 16 + lane15) * 128 + laneq * 16;
    offB[i] = (wn * 64 + i * 16 + lane15) * 128 + laneq * 16;
  }

  const f32x4 fzero = {0.f, 0.f, 0.f, 0.f};
  f32x4 acc[4][4];
#pragma unroll
  for (int m = 0; m < 4; ++m)
#pragma unroll
    for (int n = 0; n < 4; ++n) acc[m][n] = fzero;

  bf16x8 af[4][2];        // af[0..1]: loaded for next tile in PhB; af[2..3]: in PhA
  bf16x8 bfr[2][4][2];    // B frags, double-buffered by tile parity

#define LDA(m, base) do {                                             \
    af[m][0] = *(const bf16x8*)((base) + ((offA[m]) ^ swz));          \
    af[m][1] = *(const bf16x8*)((base) + ((offA[m] + 64) ^ swz));     \
  } while (0)
#define LDB(S, n, base) do {                                          \
    bfr[S][n][0] = *(const bf16x8*)((base) + ((offB[n]) ^ swz));      \
    bfr[S][n][1] = *(const bf16x8*)((base) + ((offB[n] + 64) ^ swz)); \
  } while (0)
  // 16 MFMAs: rows {mA,mB} x cols 0..3 x kc 0,1
#define HALF(mA, mB, P) do {                                               \
    acc[mA][0] = MFMA_BF16(af[mA][0], bfr[P][0][0], acc[mA][0], 0, 0, 0);  \
    acc[mA][1] = MFMA_BF16(af[mA][0], bfr[P][1][0], acc[mA][1], 0, 0, 0);  \
    acc[mA][2] = MFMA_BF16(af[mA][0], bfr[P][2][0], acc[mA][2], 0, 0, 0);  \
    acc[mA][3] = MFMA_BF16(af[mA][0], bfr[P][3][0], acc[mA][3], 0, 0, 0);  \
    acc[mB][0] = MFMA_BF16(af[mB][0], bfr[P][0][0], acc[mB][0], 0, 0, 0);  \
    acc[mB][1] = MFMA_BF16(af[mB][0], bfr[P][1][0], acc[mB][1], 0, 0, 0);  \
    acc[mB][2] = MFMA_BF16(af[mB][0], bfr[P][2][0], acc[mB][2], 0, 0, 0);  \
    acc[mB][3] = MFMA_BF16(af[mB][0], bfr[P][3][0], acc[mB][3], 0, 0, 0);  \
    acc[mA][0] = MFMA_BF16(af[mA][1], bfr[P][0][1], acc[mA][0], 0, 0, 0);  \
    acc[mA][1] = MFMA_BF16(af[mA][1], bfr[P][1][1], acc[mA][1], 0, 0, 0);  \
    acc[mA][2] = MFMA_BF16(af[mA][1], bfr[P][2][1], acc[mA][2], 0, 0, 0);  \
    acc[mA][3] = MFMA_BF16(af[mA][1], bfr[P][3][1], acc[mA][3], 0, 0, 0);  \
    acc[mB][0] = MFMA_BF16(af[mB][1], bfr[P][0][1], acc[mB][0], 0, 0, 0);  \
    acc[mB][1] = MFMA_BF16(af[mB][1], bfr[P][1][1], acc[mB][1], 0, 0, 0);  \
    acc[mB][2] = MFMA_BF16(af[mB][1], bfr[P][2][1], acc[mB][2], 0, 0, 0);  \
    acc[mB][3] = MFMA_BF16(af[mB][1], bfr[P][3][1], acc[mB][3], 0, 0, 0);  \
  } while (0)

  // BODY(t2, P): PhA computes q0,q1 (af01 x bfr[P]) with af01/bfr[P] loaded
  // in the PREVIOUS phase; loads af23 for the current tile. PhB stages t2+2,
  // guarantees t2+1 landed (vmcnt(6)+barrier), loads ALL 12 next-tile frags,
  // then computes q2,q3 entirely from registers.
#define BODY(t2, P) do {                                                   \
    char* lac = lds + (P) * 16384;                                         \
    /* ---- PhA ---- */                                                    \
    LDA(2, lac); LDA(3, lac);                                              \
    __builtin_amdgcn_s_barrier();                                          \
    __builtin_amdgcn_s_setprio(1);                                         \
    HALF(0, 1, P);                                                         \
    __builtin_amdgcn_s_setprio(0);                                         \
    asm volatile("s_waitcnt lgkmcnt(0)" ::: "memory"); /* drain own reads */\
    __builtin_amdgcn_s_barrier();                                          \
    /* ---- PhB ---- */                                                    \
    if ((t2) + 2 < NT) {                                                   \
      STAGE((t2) + 2, P);                                                  \
      asm volatile("s_waitcnt vmcnt(6)" ::: "memory"); /* t2+1 landed */   \
    } else {                                                               \
      asm volatile("s_waitcnt vmcnt(0)" ::: "memory");                     \
    }                                                                      \
    __builtin_amdgcn_s_barrier();                                          \
    __builtin_amdgcn_sched_barrier(0);                                     \
    if ((t2) + 1 < NT) {                                                   \
      char* nac = lds + (1 - (P)) * 16384;                                 \
      char* nbc = lds + 32768 + (1 - (P)) * 32768;                         \
      LDA(0, nac); LDA(1, nac);                                            \
      LDB(1 - (P), 0, nbc); LDB(1 - (P), 1, nbc);                          \
      LDB(1 - (P), 2, nbc); LDB(1 - (P), 3, nbc);                          \
    }                                                                      \
    __builtin_amdgcn_s_setprio(1);                                         \
    HALF(2, 3, P);                                                         \
    __builtin_amdgcn_s_setprio(0);                                         \
    __builtin_amdgcn_s_barrier();                                          \
  } while (0)

  // prologue: stage tiles 0,1; wait tile 0; load its 12 "phase-ahead" frags
  STAGE(0, 0);
  STAGE(1, 1);
  asm volatile("s_waitcnt vmcnt(6)" ::: "memory");
  __builtin_amdgcn_s_barrier();
  {
    char* nac = lds;
    char* nbc = lds + 32768;
    LDA(0, nac); LDA(1, nac);
    LDB(0, 0, nbc); LDB(0, 1, nbc); LDB(0, 2, nbc); LDB(0, 3, nbc);
  }

  for (int t2 = 0; t2 < NT; t2 += 2) {
    BODY(t2, 0);
    BODY(t2 + 1, 1);
  }

  // epilogue: C/D layout col=lane&15, row=(lane>>4)*4+reg  [m89-verified]
#pragma unroll
  for (int m = 0; m < 4; ++m)
#pragma unroll
    for (int r = 0; r < 4; ++r) {
      const int row = m0 + wm * 64 + m * 16 + laneq * 4 + r;
      float* op = out + (size_t)row * NDIM + n0 + wn * 64 + lane15;
#pragma unroll
      for (int n = 0; n < 4; ++n) op[n * 16] = acc[m][n][r];
    }
#undef STAGE
#undef LDA
#undef LDB
#undef HALF
#undef BODY
}

// ---- correct-but-slow fallback if ws is too small -------------------------
__global__ void fallback_kernel(const float* __restrict__ x,
                                const int* __restrict__ w,
                                const float* __restrict__ scaler,
                                float* __restrict__ out) {
  const int n = blockIdx.x * 256 + threadIdx.x;
  const int m = blockIdx.y;
  float acc = 0.f;
  for (int s = 0; s < NBLK; ++s) {
    float p = 0.f;
    const float* xr = x + (size_t)m * KDIM + s * 128;
    const int* wr = w + (size_t)s * 128 * NDIM + n;
#pragma unroll 8
    for (int c = 0; c < 128; ++c) p += xr[c] * (float)wr[(size_t)c * NDIM];
    acc += p * scaler[s * NDIM + n];
  }
  out[(size_t)m * NDIM + n] = acc;
}

extern "C" void kernel_launch(void* const* d_in, const int* in_sizes, int n_in,
                              void* d_out, int out_size, void* d_ws, size_t ws_size,
                              hipStream_t stream) {
  (void)in_sizes; (void)n_in; (void)out_size;
  const float* x = (const float*)d_in[0];
  const int* w = (const int*)d_in[1];        // int8 values, int32 storage
  const float* sc = (const float*)d_in[2];
  float* out = (float*)d_out;

  const size_t need = (size_t)51 * 1024 * 1024;  // 16.8 MB A + 33.6 MB B^T
  if (ws_size >= need) {
    unsigned short* ab = (unsigned short*)d_ws;            // [M][K] bf16
    unsigned short* bt = ab + (size_t)MDIM * KDIM;         // [N][K] bf16
    prep_a_kernel<<<(MDIM * KDIM / 4) / 256, 256, 0, stream>>>(x, ab);
    prep_b_kernel<<<dim3(NDIM / 128, KDIM / 128), 256, 0, stream>>>(w, sc, bt);
    gemm_kernel<<<(MDIM / BM) * (NDIM / BN), 512, 0, stream>>>(ab, bt, out);
  } else {
    fallback_kernel<<<dim3(NDIM / 256, MDIM), 256, 0, stream>>>(x, w, sc, out);
  }
}